// Round 1
// baseline (3039.630 us; speedup 1.0000x reference)
//
#include <hip/hip_runtime.h>
#include <math.h>
#include <float.h>

#define VOCABSZ 50000
#define EMBSZ 128
#define HIDSZ 128
#define BSZ 16
#define TENCSZ 64
#define STEPSN 24
#define STARTTOK 2
#define NVB 196   // ceil(50000/256)

// ---------------------------------------------------------------------------
// Kernel 1: logits partials for one step.
// grid = NVB blocks x 256 threads. Thread handles one vocab row v:
// logit[b] = feat[b,:] . W_logit[v,:] + b_logit[v] for all 16 batch rows.
// Block then reduces per-row {max (with lowest-v tie-break), sum exp, argmax}.
// ---------------------------------------------------------------------------
__global__ __launch_bounds__(256) void logits_partial_kernel(
    const float* __restrict__ Wl, const float* __restrict__ bl,
    const float* __restrict__ feat_t,
    float* __restrict__ pmax, float* __restrict__ psum, int* __restrict__ pidx)
{
  __shared__ float s_lg[16][256];
  const int tid = threadIdx.x;
  const int v = blockIdx.x * 256 + tid;
  const bool valid = v < VOCABSZ;

  float acc[16];
#pragma unroll
  for (int r = 0; r < 16; ++r) acc[r] = 0.f;

  const float4* __restrict__ wrow = (const float4*)(Wl + (size_t)(valid ? v : 0) * 256);
#pragma unroll 4
  for (int k4 = 0; k4 < 64; ++k4) {
    float4 w = wrow[k4];
#pragma unroll
    for (int r = 0; r < 16; ++r) {
      float4 f = ((const float4*)(feat_t + r * 256))[k4];  // block-uniform -> s_load
      acc[r] += f.x * w.x + f.y * w.y + f.z * w.z + f.w * w.w;
    }
  }
  const float lb = valid ? bl[v] : 0.f;
#pragma unroll
  for (int r = 0; r < 16; ++r)
    s_lg[r][tid] = valid ? (acc[r] + lb) : -FLT_MAX;
  __syncthreads();

  // Phase 2: wave w reduces rows 4w..4w+3 (each wave covers all 256 entries).
  const int wave = tid >> 6, lane = tid & 63;
  for (int rr = 0; rr < 4; ++rr) {
    const int row = wave * 4 + rr;
    float vals[4];
    float m = -FLT_MAX; int mi = 0x7fffffff;
#pragma unroll
    for (int i = 0; i < 4; ++i) {
      float x = s_lg[row][lane + 64 * i];
      vals[i] = x;
      int gv = blockIdx.x * 256 + lane + 64 * i;
      if (x > m || (x == m && gv < mi)) { m = x; mi = gv; }
    }
#pragma unroll
    for (int off = 32; off > 0; off >>= 1) {
      float om = __shfl_xor(m, off);
      int omi = __shfl_xor(mi, off);
      if (om > m || (om == m && omi < mi)) { m = om; mi = omi; }
    }
    float s = 0.f;
#pragma unroll
    for (int i = 0; i < 4; ++i) s += expf(vals[i] - m);
#pragma unroll
    for (int off = 32; off > 0; off >>= 1) s += __shfl_xor(s, off);
    if (lane == 0) {
      pmax[blockIdx.x * BSZ + row] = m;
      psum[blockIdx.x * BSZ + row] = s;
      pidx[blockIdx.x * BSZ + row] = mi;
    }
  }
}

// ---------------------------------------------------------------------------
// Kernel 2: fused {reduce step rstep -> c, token, prs} + {GRU+attention for
// step gstep -> feat[gstep], h}.  grid = 16 blocks (one per batch), 256 thr.
// ---------------------------------------------------------------------------
__global__ __launch_bounds__(256) void rg_kernel(
    const float* __restrict__ enc, const float* __restrict__ inith,
    const float* __restrict__ embed,
    const float* __restrict__ W_ih, const float* __restrict__ W_hh,
    const float* __restrict__ b_ih, const float* __restrict__ b_hh,
    float* __restrict__ ws_f, int* __restrict__ ws_i,
    float* __restrict__ out, int rstep, int gstep)
{
  const int b = blockIdx.x, tid = threadIdx.x;
  float* feat = ws_f;
  float* hbuf = ws_f + (size_t)STEPSN * BSZ * 256;
  float* cbuf = hbuf + BSZ * HIDSZ;
  float* pmax = cbuf + STEPSN * BSZ;
  float* psum = pmax + NVB * BSZ;
  int* ptok = ws_i;
  int* pidx = ws_i + STEPSN * BSZ;

  __shared__ float s_wm[4]; __shared__ int s_wi[4];
  __shared__ float s_ws[4];
  __shared__ int s_tok;
  __shared__ float s_emb[EMBSZ];
  __shared__ float s_h[HIDSZ];
  __shared__ float s_hnew[HIDSZ];
  __shared__ float s_gh[3 * HIDSZ];
  __shared__ float s_probs[TENCSZ];

  const int lane = tid & 63, wave = tid >> 6;

  if (rstep >= 0) {
    float m = -FLT_MAX, s = 0.f; int mi = 0x7fffffff;
    if (tid < NVB) { m = pmax[tid * BSZ + b]; s = psum[tid * BSZ + b]; mi = pidx[tid * BSZ + b]; }
    float mm = m; int mmi = mi;
#pragma unroll
    for (int off = 32; off > 0; off >>= 1) {
      float om = __shfl_xor(mm, off); int omi = __shfl_xor(mmi, off);
      if (om > mm || (om == mm && omi < mmi)) { mm = om; mmi = omi; }
    }
    if (lane == 0) { s_wm[wave] = mm; s_wi[wave] = mmi; }
    __syncthreads();
    float gm = s_wm[0]; int gi_ = s_wi[0];
#pragma unroll
    for (int w = 1; w < 4; ++w) {
      if (s_wm[w] > gm || (s_wm[w] == gm && s_wi[w] < gi_)) { gm = s_wm[w]; gi_ = s_wi[w]; }
    }
    float e = (tid < NVB) ? s * expf(m - gm) : 0.f;
#pragma unroll
    for (int off = 32; off > 0; off >>= 1) e += __shfl_xor(e, off);
    if (lane == 0) s_ws[wave] = e;
    __syncthreads();
    if (tid == 0) {
      float tot = s_ws[0] + s_ws[1] + s_ws[2] + s_ws[3];
      cbuf[rstep * BSZ + b] = gm + logf(tot);
      ptok[rstep * BSZ + b] = gi_;
      out[(size_t)STEPSN * BSZ * VOCABSZ + rstep * BSZ + b] = (float)gi_;
      s_tok = gi_;
    }
    __syncthreads();
  }

  if (gstep >= 0) {
    const int tok = (gstep == 0) ? STARTTOK : s_tok;
    if (tid < 128) {
      s_emb[tid] = embed[(size_t)tok * EMBSZ + tid];
      s_h[tid] = (gstep == 0) ? inith[b * HIDSZ + tid] : hbuf[b * HIDSZ + tid];
    }
    __syncthreads();
    float gr = 0.f, gz = 0.f, gn = 0.f;
    if (tid < 128) {
      gr = b_ih[tid]; gz = b_ih[tid + 128]; gn = b_ih[tid + 256];
      const float* wr = W_ih + (size_t)tid * EMBSZ;
      const float* wz = W_ih + (size_t)(tid + 128) * EMBSZ;
      const float* wn = W_ih + (size_t)(tid + 256) * EMBSZ;
      for (int k = 0; k < EMBSZ; ++k) {
        float e = s_emb[k];
        gr += wr[k] * e; gz += wz[k] * e; gn += wn[k] * e;
      }
    } else {
      int j = tid - 128;
      float hr = b_hh[j], hz = b_hh[j + 128], hn = b_hh[j + 256];
      const float* wr = W_hh + (size_t)j * HIDSZ;
      const float* wz = W_hh + (size_t)(j + 128) * HIDSZ;
      const float* wn = W_hh + (size_t)(j + 256) * HIDSZ;
      for (int k = 0; k < HIDSZ; ++k) {
        float h = s_h[k];
        hr += wr[k] * h; hz += wz[k] * h; hn += wn[k] * h;
      }
      s_gh[j] = hr; s_gh[128 + j] = hz; s_gh[256 + j] = hn;
    }
    __syncthreads();
    if (tid < 128) {
      float r = 1.f / (1.f + expf(-(gr + s_gh[tid])));
      float z = 1.f / (1.f + expf(-(gz + s_gh[128 + tid])));
      float n = tanhf(gn + r * s_gh[256 + tid]);
      s_hnew[tid] = (1.f - z) * n + z * s_h[tid];
    }
    __syncthreads();
    if (tid < 64) {
      const float* ep = enc + ((size_t)b * TENCSZ + tid) * 256;
      float sc = 0.f;
      for (int k = 0; k < HIDSZ; ++k) sc += ep[k] * s_hnew[k];
      float mx = sc;
#pragma unroll
      for (int off = 32; off > 0; off >>= 1) mx = fmaxf(mx, __shfl_xor(mx, off));
      float p = expf(sc - mx);
      float su = p;
#pragma unroll
      for (int off = 32; off > 0; off >>= 1) su += __shfl_xor(su, off);
      s_probs[tid] = p / su;
    }
    __syncthreads();
    if (tid < 128) {
      float a = 0.f;
      for (int tt = 0; tt < TENCSZ; ++tt)
        a += s_probs[tt] * enc[((size_t)b * TENCSZ + tt) * 256 + tid];
      float* fptr = feat + ((size_t)gstep * BSZ + b) * 256;
      fptr[tid] = a;
      fptr[128 + tid] = s_hnew[tid];
      hbuf[b * HIDSZ + tid] = s_hnew[tid];
    }
  }
}

// ---------------------------------------------------------------------------
// Kernel 3: final materialization: out[t,b,v] = feat[t,b].W_logit[v] + bl[v] - c[t,b]
// grid = STEPSN*NVB blocks x 256 threads.
// ---------------------------------------------------------------------------
__global__ __launch_bounds__(256) void final_kernel(
    const float* __restrict__ Wl, const float* __restrict__ bl,
    const float* __restrict__ ws_f, float* __restrict__ out)
{
  const int t = blockIdx.x / NVB;
  const int vb = blockIdx.x - t * NVB;
  const int tid = threadIdx.x;
  const int v = vb * 256 + tid;
  const bool valid = v < VOCABSZ;
  const float* feat_t = ws_f + (size_t)t * BSZ * 256;
  const float* cb = ws_f + (size_t)STEPSN * BSZ * 256 + BSZ * HIDSZ + t * BSZ;

  float acc[16];
#pragma unroll
  for (int r = 0; r < 16; ++r) acc[r] = 0.f;
  const float4* wrow = (const float4*)(Wl + (size_t)(valid ? v : 0) * 256);
#pragma unroll 4
  for (int k4 = 0; k4 < 64; ++k4) {
    float4 w = wrow[k4];
#pragma unroll
    for (int r = 0; r < 16; ++r) {
      float4 f = ((const float4*)(feat_t + r * 256))[k4];
      acc[r] += f.x * w.x + f.y * w.y + f.z * w.z + f.w * w.w;
    }
  }
  if (valid) {
    float lb = bl[v];
#pragma unroll
    for (int r = 0; r < 16; ++r)
      out[((size_t)t * BSZ + r) * VOCABSZ + v] = acc[r] + lb - cb[r];
  }
}

extern "C" void kernel_launch(void* const* d_in, const int* in_sizes, int n_in,
                              void* d_out, int out_size, void* d_ws, size_t ws_size,
                              hipStream_t stream)
{
  const float* enc   = (const float*)d_in[0];
  const float* inith = (const float*)d_in[1];
  const float* embed = (const float*)d_in[2];
  const float* W_ih  = (const float*)d_in[3];
  const float* W_hh  = (const float*)d_in[4];
  const float* b_ih  = (const float*)d_in[5];
  const float* b_hh  = (const float*)d_in[6];
  const float* Wl    = (const float*)d_in[7];
  const float* bl    = (const float*)d_in[8];
  float* out = (float*)d_out;

  float* ws_f = (float*)d_ws;
  const size_t nfloats = (size_t)STEPSN * BSZ * 256 + BSZ * HIDSZ + STEPSN * BSZ
                       + 2 * (size_t)NVB * BSZ;
  int* ws_i = (int*)(ws_f + nfloats);
  float* pmax = ws_f + (size_t)STEPSN * BSZ * 256 + BSZ * HIDSZ + STEPSN * BSZ;
  float* psum = pmax + NVB * BSZ;
  int* pidx = ws_i + STEPSN * BSZ;

  // G_0: produce feat[0] from START token + initial hidden.
  rg_kernel<<<BSZ, 256, 0, stream>>>(enc, inith, embed, W_ih, W_hh, b_ih, b_hh,
                                     ws_f, ws_i, out, -1, 0);
  for (int t = 0; t < STEPSN; ++t) {
    const float* feat_t = ws_f + (size_t)t * BSZ * 256;
    logits_partial_kernel<<<NVB, 256, 0, stream>>>(Wl, bl, feat_t, pmax, psum, pidx);
    rg_kernel<<<BSZ, 256, 0, stream>>>(enc, inith, embed, W_ih, W_hh, b_ih, b_hh,
                                       ws_f, ws_i, out, t, (t < STEPSN - 1) ? (t + 1) : -1);
  }
  final_kernel<<<STEPSN * NVB, 256, 0, stream>>>(Wl, bl, ws_f, out);
}

// Round 2
// 1390.618 us; speedup vs baseline: 2.1858x; 2.1858x over previous
//
#include <hip/hip_runtime.h>
#include <math.h>
#include <float.h>

#define VOCABSZ 50000
#define EMBSZ 128
#define HIDSZ 128
#define BSZ 16
#define TENCSZ 64
#define STEPSN 24
#define STARTTOK 2
#define RPB 64
#define NBLK 782   // ceil(50000/64)

// ws float layout
#define FEAT_OFF 0
#define HBUF_OFF (STEPSN*BSZ*256)
#define CBUF_OFF (HBUF_OFF + BSZ*HIDSZ)
#define PMAX_OFF (CBUF_OFF + STEPSN*BSZ)
#define PSUM_OFF (PMAX_OFF + NBLK*BSZ)
#define WS_FLOATS (PSUM_OFF + NBLK*BSZ)
// ws int layout (after floats): pidx[NBLK*BSZ]

// ---------------------------------------------------------------------------
// Step kernel: logits for step t written directly to out[t], plus per-block
// partial {max, argmax, sum-exp} per batch row.
// grid = 782 blocks x 256 threads. Wave w handles batch rows 4w..4w+3;
// lane l handles vocab row blk*64+l. feat staged in LDS (broadcast reads).
// ---------------------------------------------------------------------------
__global__ __launch_bounds__(256) void step_kernel(
    const float* __restrict__ Wl, const float* __restrict__ bl,
    float* __restrict__ ws_f, int* __restrict__ ws_i,
    float* __restrict__ out, int t)
{
  __shared__ float s_feat[BSZ * 256];
  const int tid = threadIdx.x;
  const float* feat_t = ws_f + FEAT_OFF + (size_t)t * BSZ * 256;
  {
    const float4* src = (const float4*)feat_t;
    float4* dst = (float4*)s_feat;
    for (int i = tid; i < BSZ * 64; i += 256) dst[i] = src[i];
  }
  __syncthreads();

  const int lane = tid & 63, wave = tid >> 6;
  const int v = blockIdx.x * RPB + lane;
  const bool valid = v < VOCABSZ;
  const int r0 = wave * 4;
  const float4* wrow = (const float4*)(Wl + (size_t)(valid ? v : 0) * 256);
  const float4* f0p = (const float4*)(s_feat + (r0 + 0) * 256);
  const float4* f1p = (const float4*)(s_feat + (r0 + 1) * 256);
  const float4* f2p = (const float4*)(s_feat + (r0 + 2) * 256);
  const float4* f3p = (const float4*)(s_feat + (r0 + 3) * 256);

  float a0 = 0.f, a1 = 0.f, a2 = 0.f, a3 = 0.f;
#pragma unroll 4
  for (int k = 0; k < 64; ++k) {
    float4 w = wrow[k];
    float4 f0 = f0p[k], f1 = f1p[k], f2 = f2p[k], f3 = f3p[k];
    a0 += f0.x * w.x + f0.y * w.y + f0.z * w.z + f0.w * w.w;
    a1 += f1.x * w.x + f1.y * w.y + f1.z * w.z + f1.w * w.w;
    a2 += f2.x * w.x + f2.y * w.y + f2.z * w.z + f2.w * w.w;
    a3 += f3.x * w.x + f3.y * w.y + f3.z * w.z + f3.w * w.w;
  }
  const float lb = valid ? bl[v] : 0.f;
  float lg[4] = {a0 + lb, a1 + lb, a2 + lb, a3 + lb};
  if (valid) {
#pragma unroll
    for (int j = 0; j < 4; ++j)
      out[((size_t)t * BSZ + (r0 + j)) * VOCABSZ + v] = lg[j];
  }

  float* pmax = ws_f + PMAX_OFF;
  float* psum = ws_f + PSUM_OFF;
  int* pidx = ws_i;
#pragma unroll
  for (int j = 0; j < 4; ++j) {
    float m = valid ? lg[j] : -FLT_MAX;
    int mi = valid ? v : 0x7fffffff;
#pragma unroll
    for (int off = 32; off; off >>= 1) {
      float om = __shfl_xor(m, off);
      int oi = __shfl_xor(mi, off);
      if (om > m || (om == m && oi < mi)) { m = om; mi = oi; }
    }
    float s = valid ? expf(lg[j] - m) : 0.f;
#pragma unroll
    for (int off = 32; off; off >>= 1) s += __shfl_xor(s, off);
    if (lane == 0) {
      pmax[blockIdx.x * BSZ + (r0 + j)] = m;
      psum[blockIdx.x * BSZ + (r0 + j)] = s;
      pidx[blockIdx.x * BSZ + (r0 + j)] = mi;
    }
  }
}

// ---------------------------------------------------------------------------
// rg kernel: reduce step rstep's partials -> {c, token}, then GRU+attention
// for step gstep -> feat[gstep], h.  grid = 16 blocks (one per batch).
// ---------------------------------------------------------------------------
__global__ __launch_bounds__(256) void rg_kernel(
    const float* __restrict__ enc, const float* __restrict__ inith,
    const float* __restrict__ embed,
    const float* __restrict__ W_ih, const float* __restrict__ W_hh,
    const float* __restrict__ b_ih, const float* __restrict__ b_hh,
    float* __restrict__ ws_f, int* __restrict__ ws_i,
    float* __restrict__ out, int rstep, int gstep)
{
  const int b = blockIdx.x, tid = threadIdx.x;
  float* feat = ws_f + FEAT_OFF;
  float* hbuf = ws_f + HBUF_OFF;
  float* cbuf = ws_f + CBUF_OFF;
  float* pmax = ws_f + PMAX_OFF;
  float* psum = ws_f + PSUM_OFF;
  int* pidx = ws_i;

  __shared__ float s_wm[4]; __shared__ int s_wi[4];
  __shared__ float s_ws[4];
  __shared__ int s_tok;
  __shared__ float s_emb[EMBSZ];
  __shared__ float s_h[HIDSZ];
  __shared__ float s_hnew[HIDSZ];
  __shared__ float s_gh[3 * HIDSZ];
  __shared__ float s_probs[TENCSZ];

  const int lane = tid & 63, wave = tid >> 6;

  if (rstep >= 0) {
    float m = -FLT_MAX; int mi = 0x7fffffff;
    for (int i = tid; i < NBLK; i += 256) {
      float mm = pmax[i * BSZ + b]; int ii = pidx[i * BSZ + b];
      if (mm > m || (mm == m && ii < mi)) { m = mm; mi = ii; }
    }
#pragma unroll
    for (int off = 32; off; off >>= 1) {
      float om = __shfl_xor(m, off); int oi = __shfl_xor(mi, off);
      if (om > m || (om == m && oi < mi)) { m = om; mi = oi; }
    }
    if (lane == 0) { s_wm[wave] = m; s_wi[wave] = mi; }
    __syncthreads();
    float gm = s_wm[0]; int gi_ = s_wi[0];
#pragma unroll
    for (int w = 1; w < 4; ++w) {
      if (s_wm[w] > gm || (s_wm[w] == gm && s_wi[w] < gi_)) { gm = s_wm[w]; gi_ = s_wi[w]; }
    }
    float e = 0.f;
    for (int i = tid; i < NBLK; i += 256)
      e += psum[i * BSZ + b] * expf(pmax[i * BSZ + b] - gm);
#pragma unroll
    for (int off = 32; off; off >>= 1) e += __shfl_xor(e, off);
    if (lane == 0) s_ws[wave] = e;
    __syncthreads();
    if (tid == 0) {
      float tot = s_ws[0] + s_ws[1] + s_ws[2] + s_ws[3];
      cbuf[rstep * BSZ + b] = gm + logf(tot);
      out[(size_t)STEPSN * BSZ * VOCABSZ + rstep * BSZ + b] = (float)gi_;
      s_tok = gi_;
    }
    __syncthreads();
  }

  if (gstep >= 0) {
    const int tok = (gstep == 0) ? STARTTOK : s_tok;
    if (tid < 128) {
      s_emb[tid] = embed[(size_t)tok * EMBSZ + tid];
      s_h[tid] = (gstep == 0) ? inith[b * HIDSZ + tid] : hbuf[b * HIDSZ + tid];
    }
    __syncthreads();
    float gr = 0.f, gz = 0.f, gn = 0.f;
    if (tid < 128) {
      gr = b_ih[tid]; gz = b_ih[tid + 128]; gn = b_ih[tid + 256];
      const float* wr = W_ih + (size_t)tid * EMBSZ;
      const float* wz = W_ih + (size_t)(tid + 128) * EMBSZ;
      const float* wn = W_ih + (size_t)(tid + 256) * EMBSZ;
      for (int k = 0; k < EMBSZ; ++k) {
        float e = s_emb[k];
        gr += wr[k] * e; gz += wz[k] * e; gn += wn[k] * e;
      }
    } else {
      int j = tid - 128;
      float hr = b_hh[j], hz = b_hh[j + 128], hn = b_hh[j + 256];
      const float* wr = W_hh + (size_t)j * HIDSZ;
      const float* wz = W_hh + (size_t)(j + 128) * HIDSZ;
      const float* wn = W_hh + (size_t)(j + 256) * HIDSZ;
      for (int k = 0; k < HIDSZ; ++k) {
        float h = s_h[k];
        hr += wr[k] * h; hz += wz[k] * h; hn += wn[k] * h;
      }
      s_gh[j] = hr; s_gh[128 + j] = hz; s_gh[256 + j] = hn;
    }
    __syncthreads();
    if (tid < 128) {
      float r = 1.f / (1.f + expf(-(gr + s_gh[tid])));
      float z = 1.f / (1.f + expf(-(gz + s_gh[128 + tid])));
      float n = tanhf(gn + r * s_gh[256 + tid]);
      s_hnew[tid] = (1.f - z) * n + z * s_h[tid];
    }
    __syncthreads();
    if (tid < 64) {
      const float* ep = enc + ((size_t)b * TENCSZ + tid) * 256;
      float sc = 0.f;
      for (int k = 0; k < HIDSZ; ++k) sc += ep[k] * s_hnew[k];
      float mx = sc;
#pragma unroll
      for (int off = 32; off; off >>= 1) mx = fmaxf(mx, __shfl_xor(mx, off));
      float p = expf(sc - mx);
      float su = p;
#pragma unroll
      for (int off = 32; off; off >>= 1) su += __shfl_xor(su, off);
      s_probs[tid] = p / su;
    }
    __syncthreads();
    if (tid < 128) {
      float a = 0.f;
      for (int tt = 0; tt < TENCSZ; ++tt)
        a += s_probs[tt] * enc[((size_t)b * TENCSZ + tt) * 256 + tid];
      float* fptr = feat + ((size_t)gstep * BSZ + b) * 256;
      fptr[tid] = a;
      fptr[128 + tid] = s_hnew[tid];
      hbuf[b * HIDSZ + tid] = s_hnew[tid];
    }
  }
}

// ---------------------------------------------------------------------------
// Subtract kernel: out[t,b,v] -= c[t,b], in place. 8 floats/thread.
// grid = 19.2M/8/256 = 9375 blocks exactly.
// ---------------------------------------------------------------------------
__global__ __launch_bounds__(256) void subtract_kernel(
    const float* __restrict__ cbuf, float* __restrict__ out)
{
  size_t i = ((size_t)blockIdx.x * 256 + threadIdx.x) * 8;
  int row = (int)(i / VOCABSZ);   // = t*16+b; 8 | VOCABSZ so no row straddle
  float c = cbuf[row];
  float4* p = (float4*)(out + i);
  float4 x0 = p[0], x1 = p[1];
  x0.x -= c; x0.y -= c; x0.z -= c; x0.w -= c;
  x1.x -= c; x1.y -= c; x1.z -= c; x1.w -= c;
  p[0] = x0; p[1] = x1;
}

extern "C" void kernel_launch(void* const* d_in, const int* in_sizes, int n_in,
                              void* d_out, int out_size, void* d_ws, size_t ws_size,
                              hipStream_t stream)
{
  const float* enc   = (const float*)d_in[0];
  const float* inith = (const float*)d_in[1];
  const float* embed = (const float*)d_in[2];
  const float* W_ih  = (const float*)d_in[3];
  const float* W_hh  = (const float*)d_in[4];
  const float* b_ih  = (const float*)d_in[5];
  const float* b_hh  = (const float*)d_in[6];
  const float* Wl    = (const float*)d_in[7];
  const float* bl    = (const float*)d_in[8];
  float* out = (float*)d_out;

  float* ws_f = (float*)d_ws;
  int* ws_i = (int*)(ws_f + WS_FLOATS);

  rg_kernel<<<BSZ, 256, 0, stream>>>(enc, inith, embed, W_ih, W_hh, b_ih, b_hh,
                                     ws_f, ws_i, out, -1, 0);
  for (int t = 0; t < STEPSN; ++t) {
    step_kernel<<<NBLK, 256, 0, stream>>>(Wl, bl, ws_f, ws_i, out, t);
    rg_kernel<<<BSZ, 256, 0, stream>>>(enc, inith, embed, W_ih, W_hh, b_ih, b_hh,
                                       ws_f, ws_i, out, t, (t < STEPSN - 1) ? (t + 1) : -1);
  }
  subtract_kernel<<<(STEPSN * BSZ * VOCABSZ / 8) / 256, 256, 0, stream>>>(
      ws_f + CBUF_OFF, out);
}

// Round 3
// 1354.895 us; speedup vs baseline: 2.2434x; 1.0264x over previous
//
#include <hip/hip_runtime.h>
#include <math.h>
#include <float.h>

#define VOCABSZ 50000
#define EMBSZ 128
#define HIDSZ 128
#define BSZ 16
#define TENCSZ 64
#define STEPSN 24
#define STARTTOK 2
#define RPB 64
#define NBLK 782   // ceil(50000/64)

// ws float layout
#define FEAT_OFF 0
#define HBUF_OFF (STEPSN*BSZ*256)
#define CBUF_OFF (HBUF_OFF + BSZ*HIDSZ)
#define PMAX_OFF (CBUF_OFF + STEPSN*BSZ)
#define PSUM_OFF (PMAX_OFF + NBLK*BSZ)
#define WS_FLOATS (PSUM_OFF + NBLK*BSZ)
// ws int layout (after floats): pidx[NBLK*BSZ], layout [b][blk]

// ---------------------------------------------------------------------------
// Step kernel v3: logits for step t -> out[t], per-block softmax partials,
// plus folded subtract of c[t-1] from out[t-1] (same vocab slice).
// grid = 782 x 256. Wave w owns batch rows 4w..4w+3 (feat rows via
// wave-uniform scalar loads); lane owns vocab row v = blk*64+lane.
// No LDS: feat on SMEM pipe, W on VMEM pipe, FMA on VALU pipe.
// ---------------------------------------------------------------------------
__global__ __launch_bounds__(256) void step_kernel(
    const float* __restrict__ Wl, const float* __restrict__ bl,
    const float* __restrict__ ws_f_c, float* __restrict__ ws_f,
    int* __restrict__ ws_i, float* __restrict__ out, int t)
{
  const int tid = threadIdx.x;
  const int lane = tid & 63;
  const int waveu = __builtin_amdgcn_readfirstlane(tid >> 6);
  const int r0 = waveu * 4;
  const int v = blockIdx.x * RPB + lane;
  const bool valid = v < VOCABSZ;

  const float* feat_t = ws_f_c + FEAT_OFF + (size_t)t * BSZ * 256;
  const float4* __restrict__ fb = (const float4*)(feat_t + r0 * 256);  // rows r0..r0+3
  const float4* __restrict__ wrow = (const float4*)(Wl + (size_t)(valid ? v : 0) * 256);

  float a0 = 0.f, a1 = 0.f, a2 = 0.f, a3 = 0.f;
#pragma unroll 4
  for (int k = 0; k < 64; ++k) {
    float4 w = wrow[k];
    float4 f0 = fb[k];
    float4 f1 = fb[64 + k];
    float4 f2 = fb[128 + k];
    float4 f3 = fb[192 + k];
    a0 += f0.x * w.x + f0.y * w.y + f0.z * w.z + f0.w * w.w;
    a1 += f1.x * w.x + f1.y * w.y + f1.z * w.z + f1.w * w.w;
    a2 += f2.x * w.x + f2.y * w.y + f2.z * w.z + f2.w * w.w;
    a3 += f3.x * w.x + f3.y * w.y + f3.z * w.z + f3.w * w.w;
  }
  const float lb = valid ? bl[v] : 0.f;
  float lg[4] = {a0 + lb, a1 + lb, a2 + lb, a3 + lb};

  if (valid) {
#pragma unroll
    for (int j = 0; j < 4; ++j)
      out[((size_t)t * BSZ + (r0 + j)) * VOCABSZ + v] = lg[j];
    // Folded subtract: apply c[t-1] to our slice of out[t-1].
    if (t > 0) {
      const float* cb = ws_f_c + CBUF_OFF + (t - 1) * BSZ;
#pragma unroll
      for (int j = 0; j < 4; ++j) {
        size_t idx = ((size_t)(t - 1) * BSZ + (r0 + j)) * VOCABSZ + v;
        out[idx] = out[idx] - cb[r0 + j];
      }
    }
  }

  float* pmax = ws_f + PMAX_OFF;
  float* psum = ws_f + PSUM_OFF;
  int* pidx = ws_i;
#pragma unroll
  for (int j = 0; j < 4; ++j) {
    float m = valid ? lg[j] : -FLT_MAX;
    int mi = valid ? v : 0x7fffffff;
#pragma unroll
    for (int off = 32; off; off >>= 1) {
      float om = __shfl_xor(m, off);
      int oi = __shfl_xor(mi, off);
      if (om > m || (om == m && oi < mi)) { m = om; mi = oi; }
    }
    float s = valid ? expf(lg[j] - m) : 0.f;
#pragma unroll
    for (int off = 32; off; off >>= 1) s += __shfl_xor(s, off);
    if (lane == 0) {
      // transposed layout: [b][blk] -> lane-contiguous for the rg reduce
      pmax[(r0 + j) * NBLK + blockIdx.x] = m;
      psum[(r0 + j) * NBLK + blockIdx.x] = s;
      pidx[(r0 + j) * NBLK + blockIdx.x] = mi;
    }
  }
}

// ---------------------------------------------------------------------------
// rg kernel: reduce step rstep's partials -> {c, token}, then GRU+attention
// for step gstep -> feat[gstep], h.  grid = 16 blocks (one per batch).
// ---------------------------------------------------------------------------
__global__ __launch_bounds__(256) void rg_kernel(
    const float* __restrict__ enc, const float* __restrict__ inith,
    const float* __restrict__ embed,
    const float* __restrict__ W_ih, const float* __restrict__ W_hh,
    const float* __restrict__ b_ih, const float* __restrict__ b_hh,
    float* __restrict__ ws_f, int* __restrict__ ws_i,
    float* __restrict__ out, int rstep, int gstep)
{
  const int b = blockIdx.x, tid = threadIdx.x;
  float* feat = ws_f + FEAT_OFF;
  float* hbuf = ws_f + HBUF_OFF;
  float* cbuf = ws_f + CBUF_OFF;
  float* pmax = ws_f + PMAX_OFF;
  float* psum = ws_f + PSUM_OFF;
  int* pidx = ws_i;

  __shared__ float s_wm[4]; __shared__ int s_wi[4];
  __shared__ float s_ws[4];
  __shared__ int s_tok;
  __shared__ float s_emb[EMBSZ];
  __shared__ float s_h[HIDSZ];
  __shared__ float s_hnew[HIDSZ];
  __shared__ float s_gh[3 * HIDSZ];
  __shared__ float s_probs[TENCSZ];

  const int lane = tid & 63, wave = tid >> 6;

  if (rstep >= 0) {
    float m = -FLT_MAX; int mi = 0x7fffffff;
    for (int i = tid; i < NBLK; i += 256) {
      float mm = pmax[b * NBLK + i]; int ii = pidx[b * NBLK + i];
      if (mm > m || (mm == m && ii < mi)) { m = mm; mi = ii; }
    }
#pragma unroll
    for (int off = 32; off; off >>= 1) {
      float om = __shfl_xor(m, off); int oi = __shfl_xor(mi, off);
      if (om > m || (om == m && oi < mi)) { m = om; mi = oi; }
    }
    if (lane == 0) { s_wm[wave] = m; s_wi[wave] = mi; }
    __syncthreads();
    float gm = s_wm[0]; int gi_ = s_wi[0];
#pragma unroll
    for (int w = 1; w < 4; ++w) {
      if (s_wm[w] > gm || (s_wm[w] == gm && s_wi[w] < gi_)) { gm = s_wm[w]; gi_ = s_wi[w]; }
    }
    float e = 0.f;
    for (int i = tid; i < NBLK; i += 256)
      e += psum[b * NBLK + i] * expf(pmax[b * NBLK + i] - gm);
#pragma unroll
    for (int off = 32; off; off >>= 1) e += __shfl_xor(e, off);
    if (lane == 0) s_ws[wave] = e;
    __syncthreads();
    if (tid == 0) {
      float tot = s_ws[0] + s_ws[1] + s_ws[2] + s_ws[3];
      cbuf[rstep * BSZ + b] = gm + logf(tot);
      out[(size_t)STEPSN * BSZ * VOCABSZ + rstep * BSZ + b] = (float)gi_;
      s_tok = gi_;
    }
    __syncthreads();
  }

  if (gstep >= 0) {
    const int tok = (gstep == 0) ? STARTTOK : s_tok;
    if (tid < 128) {
      s_emb[tid] = embed[(size_t)tok * EMBSZ + tid];
      s_h[tid] = (gstep == 0) ? inith[b * HIDSZ + tid] : hbuf[b * HIDSZ + tid];
    }
    __syncthreads();
    float gr = 0.f, gz = 0.f, gn = 0.f;
    if (tid < 128) {
      gr = b_ih[tid]; gz = b_ih[tid + 128]; gn = b_ih[tid + 256];
      const float* wr = W_ih + (size_t)tid * EMBSZ;
      const float* wz = W_ih + (size_t)(tid + 128) * EMBSZ;
      const float* wn = W_ih + (size_t)(tid + 256) * EMBSZ;
      for (int k = 0; k < EMBSZ; ++k) {
        float e = s_emb[k];
        gr += wr[k] * e; gz += wz[k] * e; gn += wn[k] * e;
      }
    } else {
      int j = tid - 128;
      float hr = b_hh[j], hz = b_hh[j + 128], hn = b_hh[j + 256];
      const float* wr = W_hh + (size_t)j * HIDSZ;
      const float* wz = W_hh + (size_t)(j + 128) * HIDSZ;
      const float* wn = W_hh + (size_t)(j + 256) * HIDSZ;
      for (int k = 0; k < HIDSZ; ++k) {
        float h = s_h[k];
        hr += wr[k] * h; hz += wz[k] * h; hn += wn[k] * h;
      }
      s_gh[j] = hr; s_gh[128 + j] = hz; s_gh[256 + j] = hn;
    }
    __syncthreads();
    if (tid < 128) {
      float r = 1.f / (1.f + expf(-(gr + s_gh[tid])));
      float z = 1.f / (1.f + expf(-(gz + s_gh[128 + tid])));
      float n = tanhf(gn + r * s_gh[256 + tid]);
      s_hnew[tid] = (1.f - z) * n + z * s_h[tid];
    }
    __syncthreads();
    if (tid < 64) {
      const float* ep = enc + ((size_t)b * TENCSZ + tid) * 256;
      float sc = 0.f;
      for (int k = 0; k < HIDSZ; ++k) sc += ep[k] * s_hnew[k];
      float mx = sc;
#pragma unroll
      for (int off = 32; off; off >>= 1) mx = fmaxf(mx, __shfl_xor(mx, off));
      float p = expf(sc - mx);
      float su = p;
#pragma unroll
      for (int off = 32; off; off >>= 1) su += __shfl_xor(su, off);
      s_probs[tid] = p / su;
    }
    __syncthreads();
    if (tid < 128) {
      float a = 0.f;
      for (int tt = 0; tt < TENCSZ; ++tt)
        a += s_probs[tt] * enc[((size_t)b * TENCSZ + tt) * 256 + tid];
      float* fptr = feat + ((size_t)gstep * BSZ + b) * 256;
      fptr[tid] = a;
      fptr[128 + tid] = s_hnew[tid];
      hbuf[b * HIDSZ + tid] = s_hnew[tid];
    }
  }
}

// ---------------------------------------------------------------------------
// Last-step subtract: out[23,b,v] -= c[23,b]. 800000 floats, 8 per thread.
// ---------------------------------------------------------------------------
__global__ __launch_bounds__(256) void sub_last_kernel(
    const float* __restrict__ cbuf, float* __restrict__ out)
{
  size_t i = ((size_t)blockIdx.x * 256 + threadIdx.x) * 8;
  if (i >= (size_t)BSZ * VOCABSZ) return;
  int b = (int)(i / VOCABSZ);           // 8 | VOCABSZ -> no row straddle
  float c = cbuf[(STEPSN - 1) * BSZ + b];
  float4* p = (float4*)(out + (size_t)(STEPSN - 1) * BSZ * VOCABSZ + i);
  float4 x0 = p[0], x1 = p[1];
  x0.x -= c; x0.y -= c; x0.z -= c; x0.w -= c;
  x1.x -= c; x1.y -= c; x1.z -= c; x1.w -= c;
  p[0] = x0; p[1] = x1;
}

extern "C" void kernel_launch(void* const* d_in, const int* in_sizes, int n_in,
                              void* d_out, int out_size, void* d_ws, size_t ws_size,
                              hipStream_t stream)
{
  const float* enc   = (const float*)d_in[0];
  const float* inith = (const float*)d_in[1];
  const float* embed = (const float*)d_in[2];
  const float* W_ih  = (const float*)d_in[3];
  const float* W_hh  = (const float*)d_in[4];
  const float* b_ih  = (const float*)d_in[5];
  const float* b_hh  = (const float*)d_in[6];
  const float* Wl    = (const float*)d_in[7];
  const float* bl    = (const float*)d_in[8];
  float* out = (float*)d_out;

  float* ws_f = (float*)d_ws;
  int* ws_i = (int*)(ws_f + WS_FLOATS);

  rg_kernel<<<BSZ, 256, 0, stream>>>(enc, inith, embed, W_ih, W_hh, b_ih, b_hh,
                                     ws_f, ws_i, out, -1, 0);
  for (int t = 0; t < STEPSN; ++t) {
    step_kernel<<<NBLK, 256, 0, stream>>>(Wl, bl, ws_f, ws_f, ws_i, out, t);
    rg_kernel<<<BSZ, 256, 0, stream>>>(enc, inith, embed, W_ih, W_hh, b_ih, b_hh,
                                       ws_f, ws_i, out, t, (t < STEPSN - 1) ? (t + 1) : -1);
  }
  const int nsub = (BSZ * VOCABSZ / 8 + 255) / 256;
  sub_last_kernel<<<nsub, 256, 0, stream>>>(ws_f + CBUF_OFF, out);
}